// Round 11
// baseline (209.261 us; speedup 1.0000x reference)
//
#include <hip/hip_runtime.h>
#include <cfloat>
#include <stdint.h>

// KmeansVectorQuantizer: B=8, T=2048, G=8, D=64, V=1024
// Outputs (flat f32): ids[B*T*G], quantized_st[B*T*G*D], kmeans, commit, total
#define G_ 8
#define D_ 64
#define V_ 1024
#define BT_ 16384
#define TPB_ 256
#define NSLOT_ 128            // spread loss-accumulator slots
#define TOKS_ 128             // tokens per scan block
#define CWC_ 256              // codewords per chunk (4 chunks)
#define DH_ 16                // d-slice per phase (16 phases, dbuf CT)
#define XROW_ 140             // staggered XT row stride (floats)
#define CTS_ 260              // CT row stride (floats)

typedef unsigned long long u64;
typedef uint32_t u32;
typedef float v2f __attribute__((ext_vector_type(2)));

#if __has_builtin(__builtin_elementwise_fma)
#define FMA2(A, B, C) __builtin_elementwise_fma((A), (B), (C))
#else
static __device__ __forceinline__ v2f FMA2(v2f a, v2f b, v2f c) {
    v2f r; r.x = fmaf(a.x, b.x, c.x); r.y = fmaf(a.y, b.y, c.y); return r;
}
#endif

// ws layout (bytes):
//   [0..511]    float part[128]     loss partial slots (memset 0)
//   [512..515]  int   cnt_active    (memset 0)
//   [1024)      float csqT[G_*V_]   32 KB  (transposed [g][v])
//   [33792)     int   list[BT_]     64 KB

// token-group stagger for XT (2-way max on b128 reads)
__device__ __forceinline__ int xoff(int tg) { return tg * 8 + (tg >> 2) * 4; }
// CT column swizzle: XOR per 32-block -> INJECTIVE (R10's additive version
// collided cw 60..63 with 64..67 -> wrong argmin). Read groups of 4 must
// compute ccol per group base; within a 4-group ccol(c+k)=ccol(c)+k.
__device__ __forceinline__ int ccol(int c) { return c ^ (((c >> 5) & 1) << 2); }

// Fused prep: csq transpose, block-aggregated active compaction (1 atomic/block),
// and in-block coalesced zero-fill of padded tokens.
__global__ void prep_csq(const float* __restrict__ cb, const int* __restrict__ pad,
                         float* __restrict__ csqT,
                         int* __restrict__ cnt, int* __restrict__ list,
                         float* __restrict__ out_ids, float* __restrict__ out_q) {
    const int tid = threadIdx.x;
    const int idx = blockIdx.x * TPB_ + tid;     // < BT_ (exact grid)

    if (idx < V_ * G_) {
        const float4* r = (const float4*)(cb + (size_t)idx * D_);
        float s = 0.f;
#pragma unroll
        for (int i = 0; i < D_ / 4; ++i) {
            float4 c = r[i];
            s += c.x * c.x + c.y * c.y + c.z * c.z + c.w * c.w;
        }
        csqT[(idx & (G_ - 1)) * V_ + (idx >> 3)] = s;
    }

    __shared__ int s_cnt[8];          // [0..3] active per wave, [4..7] padded
    __shared__ int s_base, s_npl;
    __shared__ int s_plist[TPB_];     // block-local padded tokens
    const int lane = tid & 63, w = tid >> 6;
    const bool active = (pad[idx] == 0);
    u64 bal = __ballot(active);
    int na  = __popcll(bal);
    if (lane == 0) { s_cnt[w] = na; s_cnt[4 + w] = 64 - na; }
    __syncthreads();
    if (tid == 0) {
        int ta = s_cnt[0] + s_cnt[1] + s_cnt[2] + s_cnt[3];
        s_base = atomicAdd(cnt, ta);
        s_npl  = TPB_ - ta;
    }
    __syncthreads();
    int pre_a = 0, pre_p = 0;
    for (int i = 0; i < w; ++i) { pre_a += s_cnt[i]; pre_p += s_cnt[4 + i]; }
    const u64 mb = ((u64)1 << lane) - 1;
    if (active) list[s_base + pre_a + __popcll(bal & mb)] = idx;
    else        s_plist[pre_p + __popcll(~bal & mb)] = idx;
    __syncthreads();

    const int npl = s_npl;
    for (int i = w; i < npl; i += 4) {
        int tok = s_plist[i];
        float4 z = make_float4(0.f, 0.f, 0.f, 0.f);
        float4* q = (float4*)(out_q + (size_t)tok * (G_ * D_)) + lane * 2;
        q[0] = z;
        q[1] = z;
        if (lane < G_) out_ids[(size_t)tok * G_ + lane] = -1.0f;
    }
}

// Scan: block = 128 tok x 1024 cw; thread = 8 tok x 16 cw acc (float2 pairs).
// 16 phases of (256 cw x 16 d); CT double-buffered, ONE barrier per phase;
// phase p+1's codebook is in registers during phase p's compute. CT layout:
// stride 260 + injective XOR column swizzle -> 4 disjoint bank-quads per wave
// read group (conflict-free); writes 2-way b32 (free). fma(c,x,acc) is
// bit-identical to R7-R9's fmaf(x,c,acc) chain (same d order, same v order).
__global__ __launch_bounds__(TPB_, 2) void vq_scan(
    const float* __restrict__ inp,
    const float* __restrict__ cb,
    const float* __restrict__ csqT,
    const int* __restrict__ cnt,
    const int* __restrict__ list,
    float* __restrict__ out_ids,
    float* __restrict__ out_q,
    float* __restrict__ part) {

    __shared__ __align__(16) float XT[D_ * XROW_];     // 35840 B
    __shared__ __align__(16) float CT[2][DH_ * CTS_];  // 33280 B
    __shared__ float csq_s[V_];                        //  4096 B
    __shared__ u64 merge_s[4 * TOKS_];                 //  4096 B
    __shared__ u64 win_s[TOKS_];                       //  1024 B

    const int nact = cnt[0];
    const int tile = blockIdx.x;
    if (tile * TOKS_ >= nact) return;          // uniform early-exit
    const int g   = blockIdx.y;
    const int tid = threadIdx.x;

    // ---- stage X^T (staggered) once: 2 threads per token ----
    {
        int tl = tid >> 1, dh = tid & 1;
        int p  = tile * TOKS_ + tl;
        int tok = list[p < nact ? p : 0];
        const float4* xr =
            (const float4*)(inp + (size_t)tok * (G_ * D_) + g * D_ + dh * 32);
        int base = xoff(tl >> 3) + (tl & 7);
#pragma unroll
        for (int k = 0; k < 8; ++k) {
            float4 v = xr[k];
            int d = dh * 32 + k * 4;
            XT[(d + 0) * XROW_ + base] = v.x;
            XT[(d + 1) * XROW_ + base] = v.y;
            XT[(d + 2) * XROW_ + base] = v.z;
            XT[(d + 3) * XROW_ + base] = v.w;
        }
    }
#pragma unroll
    for (int k = 0; k < 4; ++k)
        csq_s[k * 256 + tid] = csqT[g * V_ + k * 256 + tid];

    const int tg  = tid & 15;      // token group (8 tokens)
    const int cg  = tid >> 4;      // cw group (16 cw per chunk)
    const int xb0 = xoff(tg);
    // per-group swizzled CT read bases (ccol is NOT additive across groups)
    const int cbs0 = ccol(cg * 16 + 0);
    const int cbs1 = ccol(cg * 16 + 4);
    const int cbs2 = ccol(cg * 16 + 8);
    const int cbs3 = ccol(cg * 16 + 12);
    const int wcol = ccol(tid);    // swizzled CT write column (this thread's cw)

    float bestd[8];
    int   bestid[8];
#pragma unroll
    for (int i = 0; i < 8; ++i) { bestd[i] = FLT_MAX; bestid[i] = 0; }

    // prefetch/stage helpers: phase p covers chunk c=p>>2, d-slice h=p&3
    float4 pre[4];
    auto fetch = [&](int p) {
        const int c = p >> 2, h = p & 3;
        const float4* src = (const float4*)(
            cb + ((size_t)(c * CWC_ + tid) * G_ + g) * D_ + h * DH_);
#pragma unroll
        for (int k = 0; k < 4; ++k) pre[k] = src[k];
    };
    auto stage = [&](int b) {
#pragma unroll
        for (int k = 0; k < 4; ++k) {
            int dl = k * 4;
            CT[b][(dl + 0) * CTS_ + wcol] = pre[k].x;
            CT[b][(dl + 1) * CTS_ + wcol] = pre[k].y;
            CT[b][(dl + 2) * CTS_ + wcol] = pre[k].z;
            CT[b][(dl + 3) * CTS_ + wcol] = pre[k].w;
        }
    };

    fetch(0);
    stage(0);
    fetch(1);
    __syncthreads();                            // CT[0] ready (also covers XT/csq)

    v2f acc[8][8];

    for (int p = 0; p < 16; ++p) {
        const int b = p & 1, c = p >> 2, h = p & 3;
        if (p < 15) stage(b ^ 1);               // phase p+1 -> other buffer
        if (p < 14) fetch(p + 2);               // latency hidden by compute

        if (h == 0) {
            v2f z; z.x = 0.f; z.y = 0.f;
#pragma unroll
            for (int i = 0; i < 8; ++i)
#pragma unroll
                for (int j = 0; j < 8; ++j) acc[i][j] = z;
        }

#pragma unroll 2
        for (int dl = 0; dl < DH_; ++dl) {
            const int d = h * DH_ + dl;
            float4 xa = *(const float4*)&XT[d * XROW_ + xb0];
            float4 xb = *(const float4*)&XT[d * XROW_ + xb0 + 4];
            float4 c0 = *(const float4*)&CT[b][dl * CTS_ + cbs0];
            float4 c1 = *(const float4*)&CT[b][dl * CTS_ + cbs1];
            float4 c2 = *(const float4*)&CT[b][dl * CTS_ + cbs2];
            float4 c3 = *(const float4*)&CT[b][dl * CTS_ + cbs3];
            float xs[8] = {xa.x, xa.y, xa.z, xa.w, xb.x, xb.y, xb.z, xb.w};
            v2f cp[8];
            cp[0].x = c0.x; cp[0].y = c0.y;  cp[1].x = c0.z; cp[1].y = c0.w;
            cp[2].x = c1.x; cp[2].y = c1.y;  cp[3].x = c1.z; cp[3].y = c1.w;
            cp[4].x = c2.x; cp[4].y = c2.y;  cp[5].x = c2.z; cp[5].y = c2.w;
            cp[6].x = c3.x; cp[6].y = c3.y;  cp[7].x = c3.z; cp[7].y = c3.w;
#pragma unroll
            for (int i = 0; i < 8; ++i) {
                v2f xv; xv.x = xs[i]; xv.y = xs[i];
#pragma unroll
                for (int j = 0; j < 8; ++j)
                    acc[i][j] = FMA2(cp[j], xv, acc[i][j]);
            }
        }

        if (h == 3) {                           // chunk complete: fold argmin
#pragma unroll
            for (int j = 0; j < 16; ++j) {
                float cq = csq_s[c * CWC_ + cg * 16 + j];
                int   v  = c * CWC_ + cg * 16 + j;
#pragma unroll
                for (int i = 0; i < 8; ++i) {
                    float a = (j & 1) ? acc[i][j >> 1].y : acc[i][j >> 1].x;
                    float dist = cq - 2.f * a;
                    if (dist < bestd[i]) { bestd[i] = dist; bestid[i] = v; }
                }
            }
        }
        __syncthreads();                        // one barrier per phase
    }

    // ---- cross-lane (cg) / cross-wave argmin merge ----
    const int lane = tid & 63;
    const int w    = tid >> 6;
    u64 pk[8];
#pragma unroll
    for (int i = 0; i < 8; ++i) {
        u32 u = __float_as_uint(bestd[i]);
        u = u ^ ((u >> 31) ? 0xFFFFFFFFu : 0x80000000u);   // sortable float
        pk[i] = ((u64)u << 32) | (u32)bestid[i];
    }
#pragma unroll
    for (int off = 16; off <= 32; off <<= 1) {             // reduce over cg
#pragma unroll
        for (int i = 0; i < 8; ++i) {
            u64 o = __shfl_xor(pk[i], off, 64);
            pk[i] = (o < pk[i]) ? o : pk[i];
        }
    }
    if (lane < 16) {
#pragma unroll
        for (int i = 0; i < 8; ++i) merge_s[w * TOKS_ + lane * 8 + i] = pk[i];
    }
    __syncthreads();
    if (tid < TOKS_) {
        u64 q = merge_s[tid];
#pragma unroll
        for (int ww = 1; ww < 4; ++ww) {
            u64 o = merge_s[ww * TOKS_ + tid];
            q = (o < q) ? o : q;
        }
        win_s[tid] = q;
    }
    __syncthreads();

    // ---- fused epilogue: ids, quantized, loss (2 threads per token) ----
    float l = 0.f;
    {
        int tl = tid >> 1, qv = tid & 1;
        int p  = tile * TOKS_ + tl;
        if (p < nact) {
            int tok = list[p];
            int id  = (int)(win_s[tl] & 0xFFFFFFFFull);
            const float4* cr = (const float4*)(cb + ((size_t)id * G_ + g) * D_) + qv * 8;
            const float4* xr = (const float4*)(inp + (size_t)tok * (G_ * D_) + g * D_) + qv * 8;
            float4* qo = (float4*)(out_q + (size_t)tok * (G_ * D_) + g * D_) + qv * 8;
#pragma unroll
            for (int k = 0; k < 8; ++k) {
                float4 cc = cr[k], xx = xr[k];
                float dx = cc.x - xx.x, dy = cc.y - xx.y;
                float dz = cc.z - xx.z, dw = cc.w - xx.w;
                l += dx * dx + dy * dy + dz * dz + dw * dw;
                qo[k] = cc;
            }
            if (qv == 0) out_ids[(size_t)tok * G_ + g] = (float)id;
        }
    }
#pragma unroll
    for (int off = 32; off > 0; off >>= 1) l += __shfl_down(l, off, 64);
    if (lane == 0) {
        int slot = ((blockIdx.y * gridDim.x + blockIdx.x) * 4 + w) & (NSLOT_ - 1);
        atomicAdd(&part[slot], l);
    }
}

__global__ void finalize_kernel(const float* __restrict__ part,
                                const int* __restrict__ cnt,
                                float* __restrict__ out_losses) {
    int lane = threadIdx.x;                    // one wave of 64
    float l = part[lane] + part[lane + 64];
#pragma unroll
    for (int off = 32; off > 0; off >>= 1) l += __shfl_down(l, off, 64);
    if (lane == 0) {
        float k = l / (float)cnt[0];
        out_losses[0] = k;        // kmeans_loss
        out_losses[1] = k;        // commitment_loss (numerically identical)
        out_losses[2] = 2.f * k;  // total (BETA=1)
    }
}

extern "C" void kernel_launch(void* const* d_in, const int* in_sizes, int n_in,
                              void* d_out, int out_size, void* d_ws, size_t ws_size,
                              hipStream_t stream) {
    const float* inp = (const float*)d_in[0];   // (8,2048,512) f32
    const int*   pad = (const int*)d_in[1];     // (8,2048) i32
    const float* cb  = (const float*)d_in[2];   // (1024,8,64) f32

    float* out   = (float*)d_out;
    float* o_ids = out;                              // B*T*G
    float* o_q   = out + (size_t)BT_ * G_;           // B*T*G*D
    float* o_ls  = o_q + (size_t)BT_ * G_ * D_;      // 3 scalars

    float* part  = (float*)d_ws;
    int*   cnt   = (int*)((char*)d_ws + 512);
    float* csqT  = (float*)((char*)d_ws + 1024);
    int*   list  = (int*)((char*)d_ws + 33792);

    hipMemsetAsync(d_ws, 0, 1024, stream);

    prep_csq<<<dim3(BT_ / TPB_), dim3(TPB_), 0, stream>>>(
        cb, pad, csqT, cnt, list, o_ids, o_q);

    dim3 grid(BT_ / TOKS_, G_);                // worst-case 128-token tiles x g
    vq_scan<<<grid, dim3(TPB_), 0, stream>>>(
        inp, cb, csqT, cnt, list, o_ids, o_q, part);

    finalize_kernel<<<1, dim3(64), 0, stream>>>(part, cnt, o_ls);
}